// Round 5
// baseline (1446.594 us; speedup 1.0000x reference)
//
#include <hip/hip_runtime.h>

// ChunkwiseDeltaAttention (MI355X/gfx950) — round 8
// B=4 L=4096 H=2048 NH=16 D=128 C=64 -> M=16384, K=2048
//
// GEMM round 8: cycle budget showed r7 pays sum(LDS 2816, MFMA 2483)+sync
// per K-step because each phase reads the fragments it consumes. Fixes:
//   * mfma_f32_32x32x16_bf16: half the MFMA instructions, 2382 vs 2075 TF
//     ceiling, same 128 acc VGPRs -> frees budget for...
//   * register read-ahead: fragment double-buffer (fa0/fb0, fa1/fb1);
//     ksub s+1's 6 ds_read_b128 issue before ksub s's 8-MFMA cluster, so
//     LDS drains under the matrix pipe (max instead of sum).
//   * 2 barriers/K-step: mid {lgkmcnt(0); barrier; sched_barrier(0)} proves
//     all cur-buf reads COMPLETED block-wide before t+2 stages overwrite
//     cur (DMA-write vs in-flight-read race); boundary {vmcnt(6); barrier;
//     sched_barrier(0)} = r7's accounting (8 of t+1's loads proven done).
//   * staging plane carried from r7 (verified): same regions, same XOR
//     swizzle family, sigma(idx)=idx&7 over 8 chunks of the 128B row
//     (BK=64), conflict-free per aligned 8-lane group.
// A-frag (32x32x16): lane l -> row=l&31, k=(l>>5)*8+e (one b128).
// C/D: col=lane&31, row=(reg&3)+8*(reg>>2)+4*(lane>>5)  [m74/m101].

typedef __bf16 bf16x8 __attribute__((ext_vector_type(8)));
typedef float f32x4 __attribute__((ext_vector_type(4)));
typedef float f32x16 __attribute__((ext_vector_type(16)));

typedef __attribute__((address_space(1))) const unsigned int g_u32;
typedef __attribute__((address_space(3))) unsigned int l_u32;

__device__ __forceinline__ void cp16(const unsigned short* g, unsigned short* l) {
  __builtin_amdgcn_global_load_lds((g_u32*)g, (l_u32*)l, 16, 0, 0);
}

__device__ __forceinline__ unsigned short f2bf(float x) {
  unsigned u = __builtin_bit_cast(unsigned, x);
  u += 0x7fffu + ((u >> 16) & 1u);          // RNE
  return (unsigned short)(u >> 16);
}
__device__ __forceinline__ float bf2f(unsigned short h) {
  return __builtin_bit_cast(float, (unsigned)h << 16);
}
__device__ __forceinline__ unsigned pk2(float a, float b) {
  return (unsigned)f2bf(a) | ((unsigned)f2bf(b) << 16);
}

// ------------------------------------------------------------- convert ----
__global__ __launch_bounds__(256) void cvt_bf16(const float* __restrict__ in,
                                                unsigned short* __restrict__ out,
                                                int n) {
  int i = (blockIdx.x * 256 + threadIdx.x) * 8;
  if (i >= n) return;
  float4 f0 = *(const float4*)(in + i);
  float4 f1 = *(const float4*)(in + i + 4);
  uint4 u;
  u.x = pk2(f0.x, f0.y); u.y = pk2(f0.z, f0.w);
  u.z = pk2(f1.x, f1.y); u.w = pk2(f1.z, f1.w);
  *(uint4*)(out + i) = u;
}

__global__ __launch_bounds__(256) void build_bias(
    const float* __restrict__ qb, const float* __restrict__ kb,
    const float* __restrict__ vb, float* __restrict__ bias_cat) {
  int i = blockIdx.x * 256 + threadIdx.x;   // 0..8191
  float v = 0.f;
  if (i < 2048) v = qb[i];
  else if (i < 4096) v = kb[i - 2048];
  else if (i < 6144) v = vb[i - 4096];
  bias_cat[i] = v;
}

// ------------------------------------------------- beta (+ hs->bf16) ------
__global__ __launch_bounds__(256) void beta_kernel(
    const float* __restrict__ hs, const float* __restrict__ bw,
    const float* __restrict__ bb, float* __restrict__ beta,
    unsigned short* __restrict__ hsb) {
  __shared__ float row[2048];
  __shared__ float part[16][17];
  const int m = blockIdx.x;
  const float* src = hs + (size_t)m * 2048;
  for (int i = threadIdx.x; i < 512; i += 256)
    ((float4*)row)[i] = ((const float4*)src)[i];
  __syncthreads();
  if (hsb) {  // fused f32->bf16 of this row
    int e = threadIdx.x * 8;
    uint4 u;
    u.x = pk2(row[e], row[e + 1]);     u.y = pk2(row[e + 2], row[e + 3]);
    u.z = pk2(row[e + 4], row[e + 5]); u.w = pk2(row[e + 6], row[e + 7]);
    *(uint4*)(hsb + (size_t)m * 2048 + e) = u;
  }
  const int h = threadIdx.x >> 4, j = threadIdx.x & 15;
  const float* w = bw + h * 2048;
  float s = 0.f;
  #pragma unroll 8
  for (int kk = 0; kk < 128; kk++) {
    int k = j + (kk << 4);
    s += row[k] * w[k];
  }
  part[h][j] = s;
  __syncthreads();
  if (threadIdx.x < 16) {
    int hh = threadIdx.x;
    float t = bb[hh];
    #pragma unroll
    for (int j2 = 0; j2 < 16; j2++) t += part[hh][j2];
    beta[(size_t)m * 16 + hh] = fmaxf(t, 0.f) + log1pf(__expf(-fabsf(t)));
  }
}

// --------------- GEMM 256x256, BK=64, 32x32x16 MFMA, reg read-ahead -------
// C[m,n] = sum_k A[m,k]*B[n,k], bf16 in. 512 threads = 8 waves (2Mx4N),
// per-wave 128x64 = 4 Mtiles x 2 Ntiles of 32x32 (f32x16 acc each).
// LDS: S[2 bufs][AX|AY|BX|BY 16KB] = 128 KiB (r7's verified layout).
//   A-X rows {0-63}U{128-191} (idx=row or row-64), A-Y {64-127}U{192-255};
//   B-X rows wn*64+0..31 (idx=wn*32+..), B-Y rows wn*64+32..63.
// Reads: A mtile mt: region (mt<2?X:Y), idx = wm*64+(mt&1)*32+(l&31);
//        B ntile nt: region (nt?Y:X),   idx = wn*32+(l&31).
//   addr = idx*128 + ((chunk ^ (idx&7))<<4), chunk = ksub*2+(lane>>5).
// Stage: r7's machinery verbatim (sidx=tid>>3, chunk tid&7, src col
//   swizzled by sidx&7; linear LDS dest per global_load_lds rule).
template <int EPI, int N, int K>
__global__ __launch_bounds__(512, 2) void gemm256(
    const unsigned short* __restrict__ A, const unsigned short* __restrict__ Bw,
    const float* __restrict__ bias, const float* __restrict__ beta,
    void* __restrict__ Cv) {
  constexpr int NT = K / 64;
  static_assert(NT >= 3, "pipeline needs >=3 K-steps");
  __shared__ __align__(16) unsigned short S[2 * 32768];   // 128 KiB
  const int tid = threadIdx.x;
  const int m0 = blockIdx.y * 256;
  const int n0 = blockIdx.x * 256;
  const int wid = tid >> 6, lane = tid & 63;
  const int wm = wid >> 2, wn = wid & 3;
  const int l31 = lane & 31, kh = lane >> 5;

  // ---- staging maps (r7, verified) ----
  const int sidx = tid >> 3;                  // 0..63
  const int sc = tid & 7;                     // 16B chunk
  const int scol = ((sc ^ (sidx & 7)) << 3);  // swizzled src elem offset
  const unsigned short* pA = A + (size_t)(m0 + sidx) * K + scol;
  const int rbx = ((sidx >> 5) << 6) + (sidx & 31);       // B-X row for sidx
  const unsigned short* pB = Bw + (size_t)(n0 + rbx) * K + scol;

  auto STG = [&](int roff /*shorts*/, const unsigned short* src) {
    cp16(src, S + roff + tid * 8);
    cp16(src + (size_t)128 * K, S + roff + 4096 + tid * 8);
  };

  // ---- read maps ----
  const int sig = l31 & 7;
  int Abase[4], Bbase[2];
  #pragma unroll
  for (int mt = 0; mt < 4; mt++)
    Abase[mt] = ((mt < 2) ? 0 : 16384) + (wm * 64 + (mt & 1) * 32 + l31) * 128;
  #pragma unroll
  for (int nt = 0; nt < 2; nt++)
    Bbase[nt] = 32768 + nt * 16384 + (wn * 32 + l31) * 128;
  const int pf0 = (((0 * 2 + kh) ^ sig) << 4);
  const int pf1 = (((1 * 2 + kh) ^ sig) << 4);
  const int pf2 = (((2 * 2 + kh) ^ sig) << 4);
  const int pf3 = (((3 * 2 + kh) ^ sig) << 4);

  f32x16 acc[4][2] = {};
  bf16x8 fa0[4], fb0[2], fa1[4], fb1[2];

  // ---- prologue: tile0 {AX,AY,BX,BY} -> buf0; tile1 {AX,BX,BY} -> buf1 ----
  STG(0,             pA);
  STG(8192,          pA + (size_t)64 * K);
  STG(16384,         pB);
  STG(24576,         pB + (size_t)32 * K);
  STG(32768,         pA + 64);
  STG(32768 + 16384, pB + 64);
  STG(32768 + 24576, pB + (size_t)32 * K + 64);
  asm volatile("s_waitcnt vmcnt(6)" ::: "memory");  // all of tile0 complete
  __builtin_amdgcn_s_barrier();
  __builtin_amdgcn_sched_barrier(0);

  for (int t = 0; t < NT; ++t) {
    const int cur = (t & 1) << 15;        // short offset of current buf
    const int nxt = 32768 - cur;
    const char* B0 = (const char*)S + cur * 2;
    const int koff1 = (t + 1 < NT ? t + 1 : NT - 1) * 64;
    const int koff2 = (t + 2 < NT ? t + 2 : NT - 1) * 64;

    // reads ksub0 -> f*0, ksub1 -> f*1 (12 b128)
    #pragma unroll
    for (int mt = 0; mt < 4; mt++) fa0[mt] = *(const bf16x8*)(B0 + Abase[mt] + pf0);
    #pragma unroll
    for (int nt = 0; nt < 2; nt++) fb0[nt] = *(const bf16x8*)(B0 + Bbase[nt] + pf0);
    #pragma unroll
    for (int mt = 0; mt < 4; mt++) fa1[mt] = *(const bf16x8*)(B0 + Abase[mt] + pf1);
    #pragma unroll
    for (int nt = 0; nt < 2; nt++) fb1[nt] = *(const bf16x8*)(B0 + Bbase[nt] + pf1);
    STG(nxt + 8192, pA + (size_t)64 * K + koff1);   // A-Y(t+1) completes nxt

    // MFMA ksub0 (lgkm-counted wait auto-inserted; 6 ksub1 reads in flight)
    __builtin_amdgcn_s_setprio(1);
    #pragma unroll
    for (int mt = 0; mt < 4; mt++)
      #pragma unroll
      for (int nt = 0; nt < 2; nt++)
        acc[mt][nt] = __builtin_amdgcn_mfma_f32_32x32x16_bf16(
            fa0[mt], fb0[nt], acc[mt][nt], 0, 0, 0);
    __builtin_amdgcn_s_setprio(0);

    // reads ksub2 -> f*0 (WAR after ksub0 cluster issue)
    #pragma unroll
    for (int mt = 0; mt < 4; mt++) fa0[mt] = *(const bf16x8*)(B0 + Abase[mt] + pf2);
    #pragma unroll
    for (int nt = 0; nt < 2; nt++) fb0[nt] = *(const bf16x8*)(B0 + Bbase[nt] + pf2);

    // MFMA ksub1
    __builtin_amdgcn_s_setprio(1);
    #pragma unroll
    for (int mt = 0; mt < 4; mt++)
      #pragma unroll
      for (int nt = 0; nt < 2; nt++)
        acc[mt][nt] = __builtin_amdgcn_mfma_f32_32x32x16_bf16(
            fa1[mt], fb1[nt], acc[mt][nt], 0, 0, 0);
    __builtin_amdgcn_s_setprio(0);

    // reads ksub3 -> f*1
    #pragma unroll
    for (int mt = 0; mt < 4; mt++) fa1[mt] = *(const bf16x8*)(B0 + Abase[mt] + pf3);
    #pragma unroll
    for (int nt = 0; nt < 2; nt++) fb1[nt] = *(const bf16x8*)(B0 + Bbase[nt] + pf3);

    // MFMA ksub2
    __builtin_amdgcn_s_setprio(1);
    #pragma unroll
    for (int mt = 0; mt < 4; mt++)
      #pragma unroll
      for (int nt = 0; nt < 2; nt++)
        acc[mt][nt] = __builtin_amdgcn_mfma_f32_32x32x16_bf16(
            fa0[mt], fb0[nt], acc[mt][nt], 0, 0, 0);
    __builtin_amdgcn_s_setprio(0);

    // mid sync: ALL cur-buf reads completed block-wide before overwriting cur
    asm volatile("s_waitcnt lgkmcnt(0)" ::: "memory");
    __builtin_amdgcn_s_barrier();
    __builtin_amdgcn_sched_barrier(0);

    // MFMA ksub3 (frags drained by lgkm(0) above; sched_barrier pins order)
    __builtin_amdgcn_s_setprio(1);
    #pragma unroll
    for (int mt = 0; mt < 4; mt++)
      #pragma unroll
      for (int nt = 0; nt < 2; nt++)
        acc[mt][nt] = __builtin_amdgcn_mfma_f32_32x32x16_bf16(
            fa1[mt], fb1[nt], acc[mt][nt], 0, 0, 0);
    __builtin_amdgcn_s_setprio(0);

    // stage t+2 {A-X,B-X,B-Y} into cur (now dead)
    STG(cur,         pA + koff2);
    STG(cur + 16384, pB + koff2);
    STG(cur + 24576, pB + (size_t)32 * K + koff2);

    // boundary: prev-issued 8 loads of t+1 proven complete (drain to 6)
    asm volatile("s_waitcnt vmcnt(6)" ::: "memory");
    __builtin_amdgcn_s_barrier();
    __builtin_amdgcn_sched_barrier(0);
  }
  asm volatile("s_waitcnt vmcnt(0)" ::: "memory");     // drain tail stages

  // epilogue; 32x32 C/D: col=lane&31, row=(reg&3)+8*(reg>>2)+4*(lane>>5)
  if (EPI == 0) {
    const int mode = n0 >> 11;              // 0:q 1:k 2:v 3:gate (256 | 2048)
    unsigned short* outp =
        (unsigned short*)Cv + (size_t)mode * ((size_t)16384 * 2048);
    #pragma unroll
    for (int nt = 0; nt < 2; nt++) {
      const int colg = n0 + wn * 64 + nt * 32 + l31;
      const int head = (colg >> 7) & 15;
      const float bv = bias[colg];
      #pragma unroll
      for (int mt = 0; mt < 4; mt++) {
        #pragma unroll
        for (int r = 0; r < 16; r++) {
          const int row = m0 + wm * 128 + mt * 32 + (r & 3) + 8 * (r >> 2) + 4 * kh;
          float x = acc[mt][nt][r] + bv;
          if (mode == 2) x *= beta[(size_t)row * 16 + head];
          if (mode == 3) x = x / (1.f + __expf(-x));
          outp[(size_t)row * 2048 + (colg & 2047)] = f2bf(x);
        }
      }
    }
  } else {
    #pragma unroll
    for (int nt = 0; nt < 2; nt++) {
      const int colg = n0 + wn * 64 + nt * 32 + l31;
      const float bv = bias[colg];
      #pragma unroll
      for (int mt = 0; mt < 4; mt++) {
        #pragma unroll
        for (int r = 0; r < 16; r++) {
          const int row = m0 + wm * 128 + mt * 32 + (r & 3) + 8 * (r >> 2) + 4 * kh;
          ((float*)Cv)[(size_t)row * N + colg] = acc[mt][nt][r] + bv;
        }
      }
    }
  }
}

// --------------------------------------------- fallback GEMM (round 1) ----
constexpr int GLDW = 40;
template <int EPI, bool ABF16>
__global__ __launch_bounds__(256) void gemm_bt(
    const void* __restrict__ Av, const float* __restrict__ Bw,
    const float* __restrict__ bias, const float* __restrict__ beta,
    void* __restrict__ Cv, int M, int N, int K) {
  __shared__ unsigned short As[128 * GLDW];
  __shared__ unsigned short Bs[128 * GLDW];
  const int tid = threadIdx.x;
  const int m0 = blockIdx.y * 128;
  const int n0 = blockIdx.x * 128;
  const int wid = tid >> 6, lane = tid & 63;
  const int wm = wid >> 1, wn = wid & 1;
  const int quad = lane >> 4, l16 = lane & 15;
  const int srow = tid >> 1, skh = (tid & 1) << 4;

  f32x4 acc[4][4] = {};
  const float* Bg = Bw + (size_t)(n0 + srow) * K + skh;

  for (int kb = 0; kb < K; kb += 32) {
    if (ABF16) {
      const unsigned short* Ag =
          (const unsigned short*)Av + (size_t)(m0 + srow) * K + kb + skh;
      uint4 u0 = ((const uint4*)Ag)[0];
      uint4 u1 = ((const uint4*)Ag)[1];
      uint4* d = (uint4*)&As[srow * GLDW + skh];
      d[0] = u0; d[1] = u1;
    } else {
      const float* Ag = (const float*)Av + (size_t)(m0 + srow) * K + kb + skh;
      float4 f0 = ((const float4*)Ag)[0];
      float4 f1 = ((const float4*)Ag)[1];
      float4 f2 = ((const float4*)Ag)[2];
      float4 f3 = ((const float4*)Ag)[3];
      unsigned* d = (unsigned*)&As[srow * GLDW + skh];
      d[0] = pk2(f0.x, f0.y); d[1] = pk2(f0.z, f0.w);
      d[2] = pk2(f1.x, f1.y); d[3] = pk2(f1.z, f1.w);
      d[4] = pk2(f2.x, f2.y); d[5] = pk2(f2.z, f2.w);
      d[6] = pk2(f3.x, f3.y); d[7] = pk2(f3.z, f3.w);
    }
    {
      const float* Bgk = Bg + kb;
      float4 f0 = ((const float4*)Bgk)[0];
      float4 f1 = ((const float4*)Bgk)[1];
      float4 f2 = ((const float4*)Bgk)[2];
      float4 f3 = ((const float4*)Bgk)[3];
      unsigned* d = (unsigned*)&Bs[srow * GLDW + skh];
      d[0] = pk2(f0.x, f0.y); d[1] = pk2(f0.z, f0.w);
      d[2] = pk2(f1.x, f1.y); d[3] = pk2(f1.z, f1.w);
      d[4] = pk2(f2.x, f2.y); d[5] = pk2(f2.z, f2.w);
      d[6] = pk2(f3.x, f3.y); d[7] = pk2(f3.z, f3.w);
    }
    __syncthreads();
    bf16x8 af[4], bfr[4];
    #pragma unroll
    for (int mi = 0; mi < 4; mi++)
      af[mi] = *(const bf16x8*)&As[(wm * 64 + mi * 16 + l16) * GLDW + (quad << 3)];
    #pragma unroll
    for (int ni = 0; ni < 4; ni++)
      bfr[ni] = *(const bf16x8*)&Bs[(wn * 64 + ni * 16 + l16) * GLDW + (quad << 3)];
    #pragma unroll
    for (int mi = 0; mi < 4; mi++)
      #pragma unroll
      for (int ni = 0; ni < 4; ni++)
        acc[mi][ni] = __builtin_amdgcn_mfma_f32_16x16x32_bf16(
            af[mi], bfr[ni], acc[mi][ni], 0, 0, 0);
    __syncthreads();
  }

  #pragma unroll
  for (int mi = 0; mi < 4; mi++) {
    #pragma unroll
    for (int r = 0; r < 4; r++) {
      const int row = m0 + wm * 64 + mi * 16 + quad * 4 + r;
      float bsc = 1.f;
      if (EPI == 1) bsc = beta[(size_t)row * 16 + blockIdx.x];
      #pragma unroll
      for (int ni = 0; ni < 4; ni++) {
        const int col = n0 + wn * 64 + ni * 16 + l16;
        float x = acc[mi][ni][r];
        if (EPI != 2) x += bias[col];
        if (EPI == 1) x *= bsc;
        if (EPI == 2) x = x / (1.f + __expf(-x));
        if (EPI == 3)
          ((float*)Cv)[(size_t)row * N + col] = x;
        else
          ((unsigned short*)Cv)[(size_t)row * N + col] = f2bf(x);
      }
    }
  }
}

// ----------------------------------------------------------- attention ----
constexpr int QK_LDW = 132;  // 264B = 66 banks = 2 mod 32: lanes spread
constexpr int GT_LDW = 66;   // 132B = 33 banks = 1 mod 32: write 16-way -> 4-way
constexpr int SS_LDW = 68;   // 136B = 34 banks = 2 mod 32

__global__ __launch_bounds__(256) void attn_kernel(
    const unsigned short* __restrict__ qn, const unsigned short* __restrict__ kn,
    const unsigned short* __restrict__ gvp, const unsigned short* __restrict__ gate,
    unsigned short* __restrict__ y) {
  __shared__ unsigned short qs[64 * QK_LDW];
  __shared__ unsigned short ks[64 * QK_LDW];
  __shared__ unsigned short gst[128 * GT_LDW];
  __shared__ unsigned short Ss[64 * SS_LDW];

  const int tid = threadIdx.x;
  const int m0 = blockIdx.x * 64;
  const int h = blockIdx.y;
  const size_t gbase = (size_t)m0 * 2048 + (size_t)h * 128;

  #pragma unroll
  for (int it = 0; it < 4; it++) {
    int e = tid + it * 256;
    int i = e >> 4;
    int c = (e & 15) << 3;
    size_t g = gbase + (size_t)i * 2048 + c;
    *(uint4*)&qs[i * QK_LDW + c] = *(const uint4*)&qn[g];
    *(uint4*)&ks[i * QK_LDW + c] = *(const uint4*)&kn[g];
    uint4 gvv = *(const uint4*)&gvp[g];
    unsigned short tmp[8];
    *(uint4*)tmp = gvv;
    #pragma unroll
    for (int t = 0; t < 8; t++) gst[(c + t) * GT_LDW + i] = tmp[t];
  }
  __syncthreads();

  {
    const int rr = tid >> 2;
    const int seg = (tid & 3) * 32;
    float ssq = 0.f, ssk = 0.f;
    #pragma unroll
    for (int k2 = 0; k2 < 32; k2 += 2) {
      unsigned uq = *(const unsigned*)&qs[rr * QK_LDW + seg + k2];
      unsigned uk = *(const unsigned*)&ks[rr * QK_LDW + seg + k2];
      float a = bf2f((unsigned short)(uq & 0xffff)), b = bf2f((unsigned short)(uq >> 16));
      float c2 = bf2f((unsigned short)(uk & 0xffff)), d2 = bf2f((unsigned short)(uk >> 16));
      ssq += a * a + b * b;
      ssk += c2 * c2 + d2 * d2;
    }
    ssq += __shfl_xor(ssq, 1); ssq += __shfl_xor(ssq, 2);
    ssk += __shfl_xor(ssk, 1); ssk += __shfl_xor(ssk, 2);
    float iq = rsqrtf(fmaxf(ssq, 1e-24f));
    float ik = rsqrtf(fmaxf(ssk, 1e-24f));
    #pragma unroll
    for (int k2 = 0; k2 < 32; k2 += 2) {
      unsigned uq = *(const unsigned*)&qs[rr * QK_LDW + seg + k2];
      unsigned uk = *(const unsigned*)&ks[rr * QK_LDW + seg + k2];
      float a = bf2f((unsigned short)(uq & 0xffff)), b = bf2f((unsigned short)(uq >> 16));
      float c2 = bf2f((unsigned short)(uk & 0xffff)), d2 = bf2f((unsigned short)(uk >> 16));
      *(unsigned*)&qs[rr * QK_LDW + seg + k2] = pk2(a * iq, b * iq);
      *(unsigned*)&ks[rr * QK_LDW + seg + k2] = pk2(c2 * ik, d2 * ik);
    }
  }
  __syncthreads();

  const int w = tid >> 6;
  const int lane = tid & 63;
  const int quad = lane >> 4, l16 = lane & 15;

  {
    f32x4 acc[4] = {};
    #pragma unroll
    for (int kst = 0; kst < 4; kst++) {
      bf16x8 a = *(const bf16x8*)&qs[(w * 16 + l16) * QK_LDW + kst * 32 + (quad << 3)];
      #pragma unroll
      for (int ni = 0; ni < 4; ni++) {
        bf16x8 b = *(const bf16x8*)&ks[(ni * 16 + l16) * QK_LDW + kst * 32 + (quad << 3)];
        acc[ni] = __builtin_amdgcn_mfma_f32_16x16x32_bf16(a, b, acc[ni], 0, 0, 0);
      }
    }
    #pragma unroll
    for (int ni = 0; ni < 4; ni++)
      #pragma unroll
      for (int r = 0; r < 4; r++) {
        int row = w * 16 + quad * 4 + r;
        int col = ni * 16 + l16;
        float val = (col <= row) ? acc[ni][r] : 0.f;
        Ss[row * SS_LDW + col] = f2bf(val);
      }
  }
  __syncthreads();

  {
    f32x4 acc[8] = {};
    #pragma unroll
    for (int kst = 0; kst < 2; kst++) {
      bf16x8 a = *(const bf16x8*)&Ss[(w * 16 + l16) * SS_LDW + kst * 32 + (quad << 3)];
      #pragma unroll
      for (int nd = 0; nd < 8; nd++) {
        bf16x8 b = *(const bf16x8*)&gst[(nd * 16 + l16) * GT_LDW + kst * 32 + (quad << 3)];
        acc[nd] = __builtin_amdgcn_mfma_f32_16x16x32_bf16(a, b, acc[nd], 0, 0, 0);
      }
    }
    #pragma unroll
    for (int nd = 0; nd < 8; nd++)
      #pragma unroll
      for (int r = 0; r < 4; r++) {
        int row = w * 16 + quad * 4 + r;
        int col = nd * 16 + l16;
        size_t g = gbase + (size_t)row * 2048 + col;
        float gt = bf2f(gate[g]);
        y[g] = f2bf(acc[nd][r] * gt);
      }
  }
}

// --------------------------------------------------------------- launch ---
extern "C" void kernel_launch(void* const* d_in, const int* in_sizes, int n_in,
                              void* d_out, int out_size, void* d_ws, size_t ws_size,
                              hipStream_t stream) {
  const float* hs   = (const float*)d_in[0];
  const float* q_w  = (const float*)d_in[1];
  const float* q_b  = (const float*)d_in[2];
  const float* k_w  = (const float*)d_in[3];
  const float* k_b  = (const float*)d_in[4];
  const float* v_w  = (const float*)d_in[5];
  const float* v_b  = (const float*)d_in[6];
  const float* b_w  = (const float*)d_in[9];
  const float* b_b  = (const float*)d_in[10];
  const float* og_w = (const float*)d_in[11];
  const float* o_w  = (const float*)d_in[12];
  const float* o_b  = (const float*)d_in[13];

  const int M = 16384, K = 2048;
  const size_t MB64 = 67108864;         // one [M,2048] bf16 buffer

  const size_t OFF_HSB  = 4 * MB64;
  const size_t OFF_WCAT = OFF_HSB + MB64;
  const size_t OFF_OWB  = OFF_WCAT + 33554432;
  const size_t OFF_BETA = OFF_OWB + 8388608;
  const size_t OFF_BIAS = OFF_BETA + 1048576;
  const size_t NEED     = OFF_BIAS + 32768;

  char* ws = (char*)d_ws;

  if (ws_size >= NEED) {
    unsigned short* qy   = (unsigned short*)ws;
    unsigned short* knb  = (unsigned short*)(ws + MB64);
    unsigned short* gv   = (unsigned short*)(ws + 2 * MB64);
    unsigned short* gate = (unsigned short*)(ws + 3 * MB64);
    unsigned short* hsb  = (unsigned short*)(ws + OFF_HSB);
    unsigned short* wcat = (unsigned short*)(ws + OFF_WCAT);
    unsigned short* owb  = (unsigned short*)(ws + OFF_OWB);
    float*          beta = (float*)(ws + OFF_BETA);
    float*          bias = (float*)(ws + OFF_BIAS);

    const int NW = 4194304;  // elems per 2048x2048 weight
    cvt_bf16<<<NW / 2048, 256, 0, stream>>>(q_w,  wcat,          NW);
    cvt_bf16<<<NW / 2048, 256, 0, stream>>>(k_w,  wcat + NW,     NW);
    cvt_bf16<<<NW / 2048, 256, 0, stream>>>(v_w,  wcat + 2 * NW, NW);
    cvt_bf16<<<NW / 2048, 256, 0, stream>>>(og_w, wcat + 3 * NW, NW);
    cvt_bf16<<<NW / 2048, 256, 0, stream>>>(o_w,  owb,           NW);
    build_bias<<<32, 256, 0, stream>>>(q_b, k_b, v_b, bias);
    beta_kernel<<<M, 256, 0, stream>>>(hs, b_w, b_b, beta, hsb);  // + hs->bf16

    gemm256<0, 8192, 2048><<<dim3(32, 64), 512, 0, stream>>>(
        hsb, wcat, bias, beta, qy);

    attn_kernel<<<dim3(256, 16), 256, 0, stream>>>(qy, knb, gv, gate, qy);

    gemm256<3, 2048, 2048><<<dim3(8, 64), 512, 0, stream>>>(
        qy, owb, o_b, nullptr, (float*)d_out);
  } else {
    // round-1 fallback (f32 pack staging), known-correct
    unsigned short* qy   = (unsigned short*)ws;
    unsigned short* knb  = (unsigned short*)(ws + MB64);
    unsigned short* gv   = (unsigned short*)(ws + 2 * MB64);
    unsigned short* gate = (unsigned short*)(ws + 3 * MB64);
    float*          beta = (float*)(ws + 4 * MB64);

    beta_kernel<<<M, 256, 0, stream>>>(hs, b_w, b_b, beta, nullptr);
    dim3 gg(16, 128);
    gemm_bt<0, false><<<gg, 256, 0, stream>>>(hs, q_w, q_b, nullptr, qy, M, 2048, K);
    gemm_bt<0, false><<<gg, 256, 0, stream>>>(hs, k_w, k_b, nullptr, knb, M, 2048, K);
    gemm_bt<1, false><<<gg, 256, 0, stream>>>(hs, v_w, v_b, beta, gv, M, 2048, K);
    gemm_bt<2, false><<<gg, 256, 0, stream>>>(hs, og_w, nullptr, nullptr, gate, M, 2048, K);
    attn_kernel<<<dim3(256, 16), 256, 0, stream>>>(qy, knb, gv, gate, qy);
    gemm_bt<3, true><<<gg, 256, 0, stream>>>(qy, o_w, o_b, nullptr, (float*)d_out, M, 2048, K);
  }
}